// Round 5
// baseline (337.945 us; speedup 1.0000x reference)
//
#include <hip/hip_runtime.h>
#include <cstdint>

#define B_  64
#define P_  196
#define C_  768
#define HS_ 384
#define M_  49152
#define RT_ 96            // r-columns per block (3 rt of 32)
#define NB_ (M_ / RT_)    // 512 blocks = exactly 2/CU

// K-chunk = 16 scalars -> 8 rbf tiles (k16) + 1 silu tile per chunk.
#define NC1 13
#define KT1 111
#define NT1 12
#define NC2 24
#define KT2 216
#define NT2 7

#define H1_ELEMS  ((size_t)M_ * HS_)
#define W1P_ELEMS ((size_t)KT1 * NT1 * 512) // 681,984
#define W2P_ELEMS ((size_t)KT2 * NT2 * 512) // 774,144

typedef __attribute__((ext_vector_type(8)))  short short8;
typedef __attribute__((ext_vector_type(16))) float f32x16;

#define MFMA(w, a, c) __builtin_amdgcn_mfma_f32_32x32x16_bf16((w), (a), (c), 0, 0, 0)

static __device__ __forceinline__ float bf2f(unsigned short u) {
    union { unsigned int i; float f; } v; v.i = ((unsigned int)u) << 16; return v.f;
}
static __device__ __forceinline__ unsigned short f2bf_rne(float f) {
    union { float f; unsigned int i; } v; v.f = f;
    unsigned int r = v.i + 0x7FFFu + ((v.i >> 16) & 1u);
    return (unsigned short)(r >> 16);
}
static __device__ __forceinline__ unsigned int pack2(float a, float b) {
    unsigned int ua = __float_as_uint(a) + 0x8000u;
    unsigned int ub = __float_as_uint(b) + 0x8000u;
    return __builtin_amdgcn_perm(ub, ua, 0x07060302u);  // [a | b] (a = low ushort)
}
// 8 RBF basis: exp(-(3.5s+3.5-j)^2) = exp2(-(u_j)^2), u_j = A*s+A - j*R,
// R = sqrt(log2 e).
static __device__ __forceinline__ short8 rbf8(float s) {
    const float Rr = 1.2011224087864498f;     // sqrt(log2 e)
    const float Aa = 4.2039284307525743f;     // 3.5 * Rr
    float t1 = __builtin_fmaf(Aa, s, Aa);
    union { short8 s8; unsigned int u[4]; } r;
#pragma unroll
    for (int q = 0; q < 4; q++) {
        float u0 = t1 - (float)(2 * q) * Rr;
        float u1 = t1 - (float)(2 * q + 1) * Rr;
        r.u[q] = pack2(__builtin_amdgcn_exp2f(-u0 * u0),
                       __builtin_amdgcn_exp2f(-u1 * u1));
    }
    return r.s8;
}
static __device__ __forceinline__ unsigned int silu2(float a, float b) {
    const float L2E = 1.4426950408889634f;
    float fa = a * __builtin_amdgcn_rcpf(1.f + __builtin_amdgcn_exp2f(-L2E * a));
    float fb = b * __builtin_amdgcn_rcpf(1.f + __builtin_amdgcn_exp2f(-L2E * b));
    return pack2(fa, fb);
}

// Weights packed as A-operand frags in consumption order (unchanged):
// w[tt][nt][lane][j] = W[n = nt*32+(lane&31)][k_logical(tt, khalf=lane>>5, j)]
__global__ void pack_w_kernel(const float* __restrict__ w1s,
                              const float* __restrict__ w1b,
                              const float* __restrict__ w2s,
                              const float* __restrict__ w2b,
                              unsigned short* __restrict__ w1p,
                              unsigned short* __restrict__ w2p) {
    size_t idx = (size_t)blockIdx.x * 256 + threadIdx.x;
    if (idx < W1P_ELEMS) {
        int j    = idx & 7;
        int lane = (idx >> 3) & 63;
        int lin  = idx >> 9;             // tt*NT1 + nt
        int nt   = lin % NT1;
        int tt   = lin / NT1;
        int cc   = (tt < 108) ? tt / 9 : 12;
        int kk   = (tt < 108) ? tt % 9 : (tt - 108);
        int ktl  = (cc < 12) ? kk : ((kk < 2) ? kk : 8);
        int n = nt * 32 + (lane & 31);
        int khalf = lane >> 5;
        float v = 0.f;
        if (ktl < 8) {
            int p = cc * 16 + ktl * 2 + khalf;
            if (p < P_) v = w1s[(size_t)n * 1568 + p * 8 + j];
        } else {
            int p = cc * 16 + khalf * 8 + j;
            if (p < P_) v = w1b[(size_t)n * 196 + p];
        }
        w1p[idx] = f2bf_rne(v);
    } else {
        size_t idx2 = idx - W1P_ELEMS;
        if (idx2 < W2P_ELEMS) {
            int j    = idx2 & 7;
            int lane = (idx2 >> 3) & 63;
            int lin  = idx2 >> 9;        // tt*NT2 + nt
            int nt   = lin % NT2;
            int tt   = lin / NT2;
            int cc   = tt / 9;
            int ktl  = tt % 9;
            int n = nt * 32 + (lane & 31);
            int khalf = lane >> 5;
            float v = 0.f;
            if (n < P_) {
                if (ktl < 8) {
                    int s = cc * 16 + ktl * 2 + khalf;
                    v = w2s[(size_t)n * 3072 + s * 8 + j];
                } else {
                    int s = cc * 16 + khalf * 8 + j;
                    v = w2b[(size_t)n * 384 + s];
                }
            }
            w2p[idx2] = f2bf_rne(v);
        }
    }
}

// R5: NO LDS, NO BARRIERS. Each lane computes its own B-operand fragment:
//   rbf tile kk, rt:  frag[j] = rbf_j( x[cc*16 + 2*kk + khalf][c0 + rt*32 + l31] )
//   silu tile, rt:    frag[j] = silu( x[cc*16 + khalf*8 + j][col] )
// Per-lane scalar loads (12 per rt per chunk): 8 "rbf slots" (k = 2i+khalf,
// khalf baked into the base pointer) + 4 "miss slots" (k = 2m+1+7*khalf)
// cover both tile types; silu selects per j with one cndmask.
// Waves are fully independent -> no produce/consume coupling, no barrier
// stalls, zero LDS traffic.

// fc1: D[n][r] = W1 * act(x)^T; writes h1t[n][r].
__global__ __launch_bounds__(256, 2)
void fc1_kernel(const float* __restrict__ x,
                const unsigned short* __restrict__ w1p,
                const float* __restrict__ b1,
                unsigned short* __restrict__ h1t) {
    int blk = blockIdx.x;
    int tid = threadIdx.x;
    int b   = blk >> 3;
    int c0  = (blk & 7) * RT_;
    const float* xb = x + (size_t)b * (P_ * C_);

    int wave = tid >> 6, lane = tid & 63;
    int l31 = lane & 31, khalf = lane >> 5;
    int half = khalf;
    int nt0 = wave * 3;

    f32x16 acc[3][3];   // [rt][nt]
#pragma unroll
    for (int rt = 0; rt < 3; rt++)
#pragma unroll
        for (int nt = 0; nt < 3; nt++)
#pragma unroll
            for (int i = 0; i < 16; i++) acc[rt][nt][i] = 0.f;

    // per-lane row-baked base pointers:
    // pr0 + rt*32 + (cc*16+2i)*C_ -> x[cc*16+2i+khalf][c0+rt*32+l31]
    // pm0 + rt*32 + (cc*16+2m)*C_ -> x[cc*16+2m+1+7*khalf][c0+rt*32+l31]
    const float* pr0 = xb + (size_t)khalf * C_ + c0 + l31;
    const float* pm0 = xb + (size_t)(1 + 7 * khalf) * C_ + c0 + l31;

    const short8* wp = (const short8*)w1p;
    short8 wbuf[2][3];
    float xr[3][8], xm[3][4];

    auto wload = [&](int d, const short8* wt0, int kk) {
        const short8* wt = wt0 + (size_t)kk * (NT1 * 64);
        wbuf[d][0] = wt[0]; wbuf[d][1] = wt[64]; wbuf[d][2] = wt[128];
    };
    auto do_mfma = [&](short8 w0, short8 w1, short8 w2,
                       short8 a0, short8 a1, short8 a2) {
        acc[0][0] = MFMA(w0, a0, acc[0][0]); acc[1][0] = MFMA(w0, a1, acc[1][0]); acc[2][0] = MFMA(w0, a2, acc[2][0]);
        acc[0][1] = MFMA(w1, a0, acc[0][1]); acc[1][1] = MFMA(w1, a1, acc[1][1]); acc[2][1] = MFMA(w1, a2, acc[2][1]);
        acc[0][2] = MFMA(w2, a0, acc[0][2]); acc[1][2] = MFMA(w2, a1, acc[1][2]); acc[2][2] = MFMA(w2, a2, acc[2][2]);
    };
    auto loadx = [&](int cc) {
#pragma unroll
        for (int rt = 0; rt < 3; rt++) {
            const float* r = pr0 + rt * 32;
            const float* m = pm0 + rt * 32;
#pragma unroll
            for (int i = 0; i < 8; i++) xr[rt][i] = r[(size_t)(cc * 16 + 2 * i) * C_];
#pragma unroll
            for (int i = 0; i < 4; i++) xm[rt][i] = m[(size_t)(cc * 16 + 2 * i) * C_];
        }
    };
    auto mk_rbf = [&](int kk, short8 (&a)[3]) {
#pragma unroll
        for (int rt = 0; rt < 3; rt++) a[rt] = rbf8(xr[rt][kk]);
    };
    auto mk_silu = [&](short8 (&a)[3]) {
#pragma unroll
        for (int rt = 0; rt < 3; rt++) {
            union { short8 s8; unsigned int u[4]; } r;
#pragma unroll
            for (int q = 0; q < 4; q++) {
                // j=2q (even): khalf? miss[q] : rbf[q]; j=2q+1: khalf? rbf[4+q] : miss[q]
                float v0 = khalf ? xm[rt][q] : xr[rt][q];
                float v1 = khalf ? xr[rt][4 + q] : xm[rt][q];
                r.u[q] = silu2(v0, v1);
            }
            a[rt] = r.s8;
        }
    };
    auto chunk = [&](int cc) {
        loadx(cc);
        const short8* wt0 = wp + ((size_t)(cc * 9) * NT1 + nt0) * 64 + lane;
        wload(0, wt0, 0); wload(1, wt0, 1);
        short8 a[3];
#pragma unroll
        for (int kk = 0; kk < 9; kk++) {
            short8 w0 = wbuf[kk & 1][0], w1 = wbuf[kk & 1][1], w2 = wbuf[kk & 1][2];
            if (kk < 7) wload(kk & 1, wt0, kk + 2);
            if (kk < 8) mk_rbf(kk, a); else mk_silu(a);
            do_mfma(w0, w1, w2, a[0], a[1], a[2]);
        }
    };

    for (int cc = 0; cc < 12; cc++) chunk(cc);

    // tail: chunk 12 (tiles ktl {0,1,8}; weights linear 108..110), clamped rows
    {
        const float* xc = xb + c0 + l31;
#pragma unroll
        for (int rt = 0; rt < 3; rt++) {
#pragma unroll
            for (int i = 0; i < 8; i++) {
                int p = 192 + 2 * i + khalf; p = (p < P_) ? p : (P_ - 1);
                xr[rt][i] = xc[(size_t)p * C_ + rt * 32];
            }
#pragma unroll
            for (int i = 0; i < 4; i++) {
                int p = 192 + 2 * i + 1 + 7 * khalf; p = (p < P_) ? p : (P_ - 1);
                xm[rt][i] = xc[(size_t)p * C_ + rt * 32];
            }
        }
        const short8* wt0 = wp + ((size_t)108 * NT1 + nt0) * 64 + lane;
        wload(0, wt0, 0); wload(1, wt0, 1);
        short8 a[3];
        {
            short8 w0 = wbuf[0][0], w1 = wbuf[0][1], w2 = wbuf[0][2];
            wload(0, wt0, 2);
            mk_rbf(0, a);
            do_mfma(w0, w1, w2, a[0], a[1], a[2]);
        }
        {
            mk_rbf(1, a);
            do_mfma(wbuf[1][0], wbuf[1][1], wbuf[1][2], a[0], a[1], a[2]);
        }
        {
            mk_silu(a);
            do_mfma(wbuf[0][0], wbuf[0][1], wbuf[0][2], a[0], a[1], a[2]);
        }
    }

    // epilogue: h1t[n][r]
#pragma unroll
    for (int nt = 0; nt < 3; nt++) {
        int n0 = (nt0 + nt) * 32 + 4 * half;
#pragma unroll
        for (int reg = 0; reg < 16; reg++) {
            int n = n0 + (reg & 3) + 8 * (reg >> 2);
            float bv = b1[n];
#pragma unroll
            for (int rt = 0; rt < 3; rt++) {
                h1t[(size_t)n * M_ + blk * RT_ + rt * 32 + l31] = f2bf_rne(acc[rt][nt][reg] + bv);
            }
        }
    }
}

// fc2: D[p][r] = W2 * act(h1)^T; out = D + b2 + x.
__global__ __launch_bounds__(256, 2)
void fc2_kernel(const unsigned short* __restrict__ h1t,
                const unsigned short* __restrict__ w2p,
                const float* __restrict__ b2,
                const float* __restrict__ x,
                float* __restrict__ out) {
    int blk = blockIdx.x;
    int tid = threadIdx.x;
    int rbase = blk * RT_;

    int wave = tid >> 6, lane = tid & 63;
    int l31 = lane & 31, khalf = lane >> 5;
    int half = khalf;
    int nt0 = wave * 2;
    int ntn = (wave < 3) ? 2 : 1;
    int off1 = (ntn > 1) ? 64 : 0;           // wave 3 dups its tile (discarded)

    f32x16 acc[3][2];   // [rt][nt]
#pragma unroll
    for (int rt = 0; rt < 3; rt++)
#pragma unroll
        for (int nt = 0; nt < 2; nt++)
#pragma unroll
            for (int i = 0; i < 16; i++) acc[rt][nt][i] = 0.f;

    const unsigned short* qr0 = h1t + (size_t)khalf * M_ + rbase + l31;
    const unsigned short* qm0 = h1t + (size_t)(1 + 7 * khalf) * M_ + rbase + l31;

    const short8* wp = (const short8*)w2p;
    short8 wbuf[2][2];
    unsigned short xrA[3][8], xmA[3][4], xrB[3][8], xmB[3][4];

    auto wload = [&](int d, const short8* wt0, int kk) {
        const short8* wt = wt0 + (size_t)kk * (NT2 * 64);
        wbuf[d][0] = wt[0]; wbuf[d][1] = wt[off1];
    };
    auto do_mfma = [&](short8 w0, short8 w1, short8 a0, short8 a1, short8 a2) {
        acc[0][0] = MFMA(w0, a0, acc[0][0]); acc[1][0] = MFMA(w0, a1, acc[1][0]); acc[2][0] = MFMA(w0, a2, acc[2][0]);
        if (ntn == 2) {
            acc[0][1] = MFMA(w1, a0, acc[0][1]); acc[1][1] = MFMA(w1, a1, acc[1][1]); acc[2][1] = MFMA(w1, a2, acc[2][1]);
        }
    };
    auto loadx = [&](int cc, unsigned short (&xr)[3][8], unsigned short (&xm)[3][4]) {
#pragma unroll
        for (int rt = 0; rt < 3; rt++) {
            const unsigned short* r = qr0 + rt * 32;
            const unsigned short* m = qm0 + rt * 32;
#pragma unroll
            for (int i = 0; i < 8; i++) xr[rt][i] = r[(size_t)(cc * 16 + 2 * i) * M_];
#pragma unroll
            for (int i = 0; i < 4; i++) xm[rt][i] = m[(size_t)(cc * 16 + 2 * i) * M_];
        }
    };
    auto mk_rbf = [&](int kk, short8 (&a)[3], unsigned short (&xr)[3][8]) {
#pragma unroll
        for (int rt = 0; rt < 3; rt++) a[rt] = rbf8(bf2f(xr[rt][kk]));
    };
    auto mk_silu = [&](short8 (&a)[3], unsigned short (&xr)[3][8], unsigned short (&xm)[3][4]) {
#pragma unroll
        for (int rt = 0; rt < 3; rt++) {
            union { short8 s8; unsigned int u[4]; } r;
#pragma unroll
            for (int q = 0; q < 4; q++) {
                float v0 = bf2f(khalf ? xm[rt][q] : xr[rt][q]);
                float v1 = bf2f(khalf ? xr[rt][4 + q] : xm[rt][q]);
                r.u[q] = silu2(v0, v1);
            }
            a[rt] = r.s8;
        }
    };
    auto chunk = [&](int cc, unsigned short (&xr)[3][8], unsigned short (&xm)[3][4],
                     unsigned short (&nxr)[3][8], unsigned short (&nxm)[3][4]) {
        const short8* wt0 = wp + ((size_t)(cc * 9) * NT2 + nt0) * 64 + lane;
        wload(0, wt0, 0); wload(1, wt0, 1);
        if (cc + 1 < NC2) loadx(cc + 1, nxr, nxm);   // prefetch (covers HBM latency)
        short8 a[3];
#pragma unroll
        for (int kk = 0; kk < 9; kk++) {
            short8 w0 = wbuf[kk & 1][0], w1 = wbuf[kk & 1][1];
            if (kk < 7) wload(kk & 1, wt0, kk + 2);
            if (kk < 8) mk_rbf(kk, a, xr); else mk_silu(a, xr, xm);
            do_mfma(w0, w1, a[0], a[1], a[2]);
        }
    };

    loadx(0, xrA, xmA);
    for (int c2 = 0; c2 < 12; c2++) {        // chunks 0..23 in pairs (static buffers)
        chunk(2 * c2,     xrA, xmA, xrB, xmB);
        chunk(2 * c2 + 1, xrB, xmB, xrA, xmA);
    }

    // epilogue: out[b,p,c] = acc + b2[p] + x[b,p,c]
    int b = blk >> 3;
    int c0 = (blk & 7) * RT_;
#pragma unroll
    for (int nt = 0; nt < 2; nt++) {
        if (nt < ntn) {
            int p0 = (nt0 + nt) * 32 + 4 * half;
#pragma unroll
            for (int reg = 0; reg < 16; reg++) {
                int p = p0 + (reg & 3) + 8 * (reg >> 2);
                if (p < P_) {
                    float bv = b2[p];
#pragma unroll
                    for (int rt = 0; rt < 3; rt++) {
                        size_t off = ((size_t)b * P_ + p) * C_ + c0 + rt * 32 + l31;
                        out[off] = acc[rt][nt][reg] + bv + x[off];
                    }
                }
            }
        }
    }
}

extern "C" void kernel_launch(void* const* d_in, const int* in_sizes, int n_in,
                              void* d_out, int out_size, void* d_ws, size_t ws_size,
                              hipStream_t stream) {
    const float* x   = (const float*)d_in[0];
    const float* w1s = (const float*)d_in[1];
    const float* w1b = (const float*)d_in[2];
    const float* b1  = (const float*)d_in[3];
    const float* w2s = (const float*)d_in[4];
    const float* w2b = (const float*)d_in[5];
    const float* b2  = (const float*)d_in[6];
    float* out = (float*)d_out;

    unsigned short* h1t = (unsigned short*)d_ws;            // 37.75 MB bf16 [n][r]
    unsigned short* w1p = h1t + H1_ELEMS;
    unsigned short* w2p = w1p + W1P_ELEMS;                  // total ~40.7 MB

    int pack_blocks = (int)((W1P_ELEMS + W2P_ELEMS) / 256);
    pack_w_kernel<<<pack_blocks, 256, 0, stream>>>(w1s, w1b, w2s, w2b, w1p, w2p);
    fc1_kernel<<<NB_, 256, 0, stream>>>(x, w1p, b1, h1t);
    fc2_kernel<<<NB_, 256, 0, stream>>>(h1t, w2p, b2, x, out);
}

// Round 6
// 291.221 us; speedup vs baseline: 1.1604x; 1.1604x over previous
//
#include <hip/hip_runtime.h>
#include <cstdint>

#define B_  64
#define P_  196
#define C_  768
#define HS_ 384
#define M_  49152
#define RT_ 96            // r-columns per block (3 rt of 32)
#define NB_ (M_ / RT_)    // 512 blocks

// K-chunk = 16 scalars -> 8 rbf tiles (k16) + 1 silu tile per chunk.
#define NC1 13
#define KT1 111
#define NT1 12
#define NC2 24
#define KT2 216
#define NT2 7

#define H1_ELEMS  ((size_t)M_ * HS_)
#define W1P_ELEMS ((size_t)KT1 * NT1 * 512) // 681,984
#define W2P_ELEMS ((size_t)KT2 * NT2 * 512) // 774,144

typedef __attribute__((ext_vector_type(8)))  short short8;
typedef __attribute__((ext_vector_type(16))) float f32x16;

#define MFMA(w, a, c) __builtin_amdgcn_mfma_f32_32x32x16_bf16((w), (a), (c), 0, 0, 0)

static __device__ __forceinline__ float bf2f(unsigned short u) {
    union { unsigned int i; float f; } v; v.i = ((unsigned int)u) << 16; return v.f;
}
static __device__ __forceinline__ unsigned short f2bf_rne(float f) {
    union { float f; unsigned int i; } v; v.f = f;
    unsigned int r = v.i + 0x7FFFu + ((v.i >> 16) & 1u);
    return (unsigned short)(r >> 16);
}
static __device__ __forceinline__ unsigned int pack2(float a, float b) {
    unsigned int ua = __float_as_uint(a) + 0x8000u;
    unsigned int ub = __float_as_uint(b) + 0x8000u;
    return __builtin_amdgcn_perm(ub, ua, 0x07060302u);  // [a | b] (a = low ushort)
}
// 8 RBF basis: exp(-(3.5s+3.5-j)^2) = exp2(-(u_j)^2), u_j = A*s+A - j*R,
// R = sqrt(log2 e).
static __device__ __forceinline__ short8 rbf8(float s) {
    const float Rr = 1.2011224087864498f;     // sqrt(log2 e)
    const float Aa = 4.2039284307525743f;     // 3.5 * Rr
    float t1 = __builtin_fmaf(Aa, s, Aa);
    union { short8 s8; unsigned int u[4]; } r;
#pragma unroll
    for (int q = 0; q < 4; q++) {
        float u0 = t1 - (float)(2 * q) * Rr;
        float u1 = t1 - (float)(2 * q + 1) * Rr;
        r.u[q] = pack2(__builtin_amdgcn_exp2f(-u0 * u0),
                       __builtin_amdgcn_exp2f(-u1 * u1));
    }
    return r.s8;
}
static __device__ __forceinline__ unsigned int silu2(float a, float b) {
    const float L2E = 1.4426950408889634f;
    float fa = a * __builtin_amdgcn_rcpf(1.f + __builtin_amdgcn_exp2f(-L2E * a));
    float fb = b * __builtin_amdgcn_rcpf(1.f + __builtin_amdgcn_exp2f(-L2E * b));
    return pack2(fa, fb);
}

// lgkm-only barrier: LDS writes must be cross-wave visible, but vmem loads
// to private registers stay in flight across it (no vmcnt(0) drain).
static __device__ __forceinline__ void block_sync_lds() {
    __builtin_amdgcn_sched_barrier(0);
    asm volatile("s_waitcnt lgkmcnt(0)" ::: "memory");
    __builtin_amdgcn_s_barrier();
    __builtin_amdgcn_sched_barrier(0);
}

// Weights packed as A-operand frags in consumption order (unchanged):
// w[tt][nt][lane][j] = W[n = nt*32+(lane&31)][k_logical(tt, khalf=lane>>5, j)]
__global__ void pack_w_kernel(const float* __restrict__ w1s,
                              const float* __restrict__ w1b,
                              const float* __restrict__ w2s,
                              const float* __restrict__ w2b,
                              unsigned short* __restrict__ w1p,
                              unsigned short* __restrict__ w2p) {
    size_t idx = (size_t)blockIdx.x * 256 + threadIdx.x;
    if (idx < W1P_ELEMS) {
        int j    = idx & 7;
        int lane = (idx >> 3) & 63;
        int lin  = idx >> 9;             // tt*NT1 + nt
        int nt   = lin % NT1;
        int tt   = lin / NT1;
        int cc   = (tt < 108) ? tt / 9 : 12;
        int kk   = (tt < 108) ? tt % 9 : (tt - 108);
        int ktl  = (cc < 12) ? kk : ((kk < 2) ? kk : 8);
        int n = nt * 32 + (lane & 31);
        int khalf = lane >> 5;
        float v = 0.f;
        if (ktl < 8) {
            int p = cc * 16 + ktl * 2 + khalf;
            if (p < P_) v = w1s[(size_t)n * 1568 + p * 8 + j];
        } else {
            int p = cc * 16 + khalf * 8 + j;
            if (p < P_) v = w1b[(size_t)n * 196 + p];
        }
        w1p[idx] = f2bf_rne(v);
    } else {
        size_t idx2 = idx - W1P_ELEMS;
        if (idx2 < W2P_ELEMS) {
            int j    = idx2 & 7;
            int lane = (idx2 >> 3) & 63;
            int lin  = idx2 >> 9;        // tt*NT2 + nt
            int nt   = lin % NT2;
            int tt   = lin / NT2;
            int cc   = tt / 9;
            int ktl  = tt % 9;
            int n = nt * 32 + (lane & 31);
            int khalf = lane >> 5;
            float v = 0.f;
            if (n < P_) {
                if (ktl < 8) {
                    int s = cc * 16 + ktl * 2 + khalf;
                    v = w2s[(size_t)n * 3072 + s * 8 + j];
                } else {
                    int s = cc * 16 + khalf * 8 + j;
                    v = w2b[(size_t)n * 384 + s];
                }
            }
            w2p[idx2] = f2bf_rne(v);
        }
    }
}

// frag LDS tile: [rt 3][khalf 2][col 32][8] = 1536 ushort; 9 tiles/chunk.
#define TS_  1536
#define FB_  (9 * TS_)   // 13824 ushort per chunk buffer
// R6: 4 chunk buffers (110.6 KB LDS, 1 block/CU), barrier every 2 chunks.
// 512 threads: waves 0-3 = consumers (weights+ds_read+MFMA only, setprio 1),
// waves 4-7 = producers (x/h1 loads + rbf/silu + ds_write only).
// Per SIMD: 1 consumer + 1 producer -> MFMA pipe fed continuously while
// produce VALU/trans runs concurrently (m114 dual-pipe overlap).

// fc1: D[n][r] = W1 * act(x)^T; writes h1t[n][r].
__global__ __launch_bounds__(512, 1)
void fc1_kernel(const float* __restrict__ x,
                const unsigned short* __restrict__ w1p,
                const float* __restrict__ b1,
                unsigned short* __restrict__ h1t) {
    __shared__ __align__(16) unsigned short frag[4 * FB_];
    int blk = blockIdx.x;
    int tid = threadIdx.x;
    int b   = blk >> 3;
    int c0  = (blk & 7) * RT_;
    const float* xb = x + (size_t)b * (P_ * C_);
    int wave = tid >> 6;

    if (wave >= 4) {
        // ---------------- producers ----------------
        int ptid = tid & 255;
        int colA = ptid & 63, scA = ptid >> 6;
        int colB = 64 + (ptid & 31), scB = ptid >> 5;
        int pbase_rbfA  = ((colA >> 5) << 9) + (colA & 31) * 8;
        int pbase_rbfB  = 1024 + (colB & 31) * 8;
        int pbase_siluA = 8 * TS_ + ((colA >> 5) << 9) + ((scA >> 1) << 8) + (colA & 31) * 8 + (scA & 1) * 4;
        int pbase_siluB = 8 * TS_ + 1024 + ((scB >> 2) << 8) + (colB & 31) * 8 + (scB & 3) * 2;

        auto loadc = [&](int cc, float (&va)[4], float (&vb)[2]) {
#pragma unroll
            for (int i = 0; i < 4; i++) {
                int p = cc * 16 + scA * 4 + i; p = (p < P_) ? p : (P_ - 1);
                va[i] = xb[(size_t)p * C_ + c0 + colA];
            }
#pragma unroll
            for (int i = 0; i < 2; i++) {
                int p = cc * 16 + scB * 2 + i; p = (p < P_) ? p : (P_ - 1);
                vb[i] = xb[(size_t)p * C_ + c0 + colB];
            }
        };
        auto produce = [&](int cc, const float (&ra)[4], const float (&rb2)[2]) {
            int fb = (cc & 3) * FB_;
#pragma unroll
            for (int i = 0; i < 4; i++) {
                int sl = scA * 4 + i;
                *(short8*)&frag[fb + (sl >> 1) * TS_ + ((sl & 1) << 8) + pbase_rbfA] = rbf8(ra[i]);
            }
#pragma unroll
            for (int i = 0; i < 2; i++) {
                int sl = scB * 2 + i;
                *(short8*)&frag[fb + (sl >> 1) * TS_ + ((sl & 1) << 8) + pbase_rbfB] = rbf8(rb2[i]);
            }
            uint2 sv;
            sv.x = silu2(ra[0], ra[1]);
            sv.y = silu2(ra[2], ra[3]);
            *(uint2*)&frag[fb + pbase_siluA] = sv;
            *(unsigned int*)&frag[fb + pbase_siluB] = silu2(rb2[0], rb2[1]);
        };

        float vA[4], uA[2], vB[4], uB[2];
        loadc(0, vA, uA); loadc(1, vB, uB);
        produce(0, vA, uA); produce(1, vB, uB);
        loadc(2, vA, uA); loadc(3, vB, uB);
        block_sync_lds();
        for (int t = 0; t < 7; t++) {
            int cP = 2 * t + 2;
            if (cP     < NC1) produce(cP,     vA, uA);
            if (cP + 1 < NC1) produce(cP + 1, vB, uB);
            int n0 = (cP + 2 < NC1) ? cP + 2 : NC1 - 1;
            int n1 = (cP + 3 < NC1) ? cP + 3 : NC1 - 1;
            loadc(n0, vA, uA); loadc(n1, vB, uB);   // consumed next iter (gap spans barrier)
            block_sync_lds();
        }
        return;
    }

    // ---------------- consumers ----------------
    __builtin_amdgcn_s_setprio(1);
    int lane = tid & 63;
    int l31 = lane & 31, half = lane >> 5;
    int nt0 = wave * 3;

    f32x16 acc[3][3];   // [rt][nt]
#pragma unroll
    for (int rt = 0; rt < 3; rt++)
#pragma unroll
        for (int nt = 0; nt < 3; nt++)
#pragma unroll
            for (int i = 0; i < 16; i++) acc[rt][nt][i] = 0.f;

    const short8* wp = (const short8*)w1p;
    short8 wbuf[2][3];

    auto wt0_of = [&](int cc) { return wp + ((size_t)(cc * 9) * NT1 + nt0) * 64 + lane; };
    auto wload = [&](int d, const short8* wt0, int kk) {
        const short8* wt = wt0 + (size_t)kk * (NT1 * 64);
        wbuf[d][0] = wt[0]; wbuf[d][1] = wt[64]; wbuf[d][2] = wt[128];
    };
    auto do_mfma = [&](short8 w0, short8 w1, short8 w2,
                       short8 a0, short8 a1, short8 a2) {
        acc[0][0] = MFMA(w0, a0, acc[0][0]); acc[1][0] = MFMA(w0, a1, acc[1][0]); acc[2][0] = MFMA(w0, a2, acc[2][0]);
        acc[0][1] = MFMA(w1, a0, acc[0][1]); acc[1][1] = MFMA(w1, a1, acc[1][1]); acc[2][1] = MFMA(w1, a2, acc[2][1]);
        acc[0][2] = MFMA(w2, a0, acc[0][2]); acc[1][2] = MFMA(w2, a1, acc[1][2]); acc[2][2] = MFMA(w2, a2, acc[2][2]);
    };
    auto consume = [&](int cc, const short8* wt0) {   // wbuf[0],[1] preloaded
        const unsigned short* fg = &frag[(cc & 3) * FB_];
        short8 a0 = *(const short8*)&fg[lane * 8];
        short8 a1 = *(const short8*)&fg[512 + lane * 8];
        short8 a2 = *(const short8*)&fg[1024 + lane * 8];
#pragma unroll
        for (int kk = 0; kk < 9; kk++) {
            short8 na0, na1, na2;
            if (kk < 8) {
                na0 = *(const short8*)&fg[(kk + 1) * TS_ + lane * 8];
                na1 = *(const short8*)&fg[(kk + 1) * TS_ + 512 + lane * 8];
                na2 = *(const short8*)&fg[(kk + 1) * TS_ + 1024 + lane * 8];
            }
            short8 w0 = wbuf[kk & 1][0], w1 = wbuf[kk & 1][1], w2 = wbuf[kk & 1][2];
            if (kk < 7) wload(kk & 1, wt0, kk + 2);
            do_mfma(w0, w1, w2, a0, a1, a2);
            if (kk < 8) { a0 = na0; a1 = na1; a2 = na2; }
        }
    };

    const short8* wtP = wt0_of(0);
    wload(0, wtP, 0); wload(1, wtP, 1);
    block_sync_lds();
    for (int t = 0; t < 7; t++) {
        if (t < 6) {
            consume(2 * t, wtP);
            const short8* wtQ = wt0_of(2 * t + 1);
            wload(0, wtQ, 0); wload(1, wtQ, 1);
            consume(2 * t + 1, wtQ);
            wtP = wt0_of(2 * t + 2);
            wload(0, wtP, 0); wload(1, wtP, 1);     // prefetch across barrier
        } else {
            // chunk 12 tail: tiles ktl {0,1,8} = linear 108..110 (wtP = wt0_of(12))
            const unsigned short* fg = &frag[(12 & 3) * FB_];
            short8 a0 = *(const short8*)&fg[lane * 8];
            short8 a1 = *(const short8*)&fg[512 + lane * 8];
            short8 a2 = *(const short8*)&fg[1024 + lane * 8];
            short8 c0v = *(const short8*)&fg[TS_ + lane * 8];
            short8 c1v = *(const short8*)&fg[TS_ + 512 + lane * 8];
            short8 c2v = *(const short8*)&fg[TS_ + 1024 + lane * 8];
            short8 s0 = *(const short8*)&fg[8 * TS_ + lane * 8];
            short8 s1 = *(const short8*)&fg[8 * TS_ + 512 + lane * 8];
            short8 s2 = *(const short8*)&fg[8 * TS_ + 1024 + lane * 8];
            do_mfma(wbuf[0][0], wbuf[0][1], wbuf[0][2], a0, a1, a2);
            wload(0, wtP, 2);
            do_mfma(wbuf[1][0], wbuf[1][1], wbuf[1][2], c0v, c1v, c2v);
            do_mfma(wbuf[0][0], wbuf[0][1], wbuf[0][2], s0, s1, s2);
        }
        block_sync_lds();
    }

    // epilogue: h1t[n][r]
#pragma unroll
    for (int nt = 0; nt < 3; nt++) {
        int n0 = (nt0 + nt) * 32 + 4 * half;
#pragma unroll
        for (int reg = 0; reg < 16; reg++) {
            int n = n0 + (reg & 3) + 8 * (reg >> 2);
            float bv = b1[n];
#pragma unroll
            for (int rt = 0; rt < 3; rt++) {
                h1t[(size_t)n * M_ + blk * RT_ + rt * 32 + l31] = f2bf_rne(acc[rt][nt][reg] + bv);
            }
        }
    }
}

// fc2: D[p][r] = W2 * act(h1)^T; out = D + b2 + x.
__global__ __launch_bounds__(512, 1)
void fc2_kernel(const unsigned short* __restrict__ h1t,
                const unsigned short* __restrict__ w2p,
                const float* __restrict__ b2,
                const float* __restrict__ x,
                float* __restrict__ out) {
    __shared__ __align__(16) unsigned short frag[4 * FB_];
    int blk = blockIdx.x;
    int tid = threadIdx.x;
    int rbase = blk * RT_;
    int wave = tid >> 6;

    if (wave >= 4) {
        // ---------------- producers ----------------
        int ptid = tid & 255;
        int colA = ptid & 63, scA = ptid >> 6;
        int colB = 64 + (ptid & 31), scB = ptid >> 5;
        int pbase_rbfA  = ((colA >> 5) << 9) + (colA & 31) * 8;
        int pbase_rbfB  = 1024 + (colB & 31) * 8;
        int pbase_siluA = 8 * TS_ + ((colA >> 5) << 9) + ((scA >> 1) << 8) + (colA & 31) * 8 + (scA & 1) * 4;
        int pbase_siluB = 8 * TS_ + 1024 + ((scB >> 2) << 8) + (colB & 31) * 8 + (scB & 3) * 2;

        auto loadc = [&](int cc, unsigned short (&va)[4], unsigned short (&vb)[2]) {
#pragma unroll
            for (int i = 0; i < 4; i++) {
                int s = cc * 16 + scA * 4 + i; s = (s < HS_) ? s : (HS_ - 1);
                va[i] = h1t[(size_t)s * M_ + rbase + colA];
            }
#pragma unroll
            for (int i = 0; i < 2; i++) {
                int s = cc * 16 + scB * 2 + i; s = (s < HS_) ? s : (HS_ - 1);
                vb[i] = h1t[(size_t)s * M_ + rbase + colB];
            }
        };
        auto produce = [&](int cc, const unsigned short (&ra)[4], const unsigned short (&rb2)[2]) {
            int fb = (cc & 3) * FB_;
            float v0 = bf2f(ra[0]), v1 = bf2f(ra[1]), v2 = bf2f(ra[2]), v3 = bf2f(ra[3]);
            float u0 = bf2f(rb2[0]), u1 = bf2f(rb2[1]);
            float vv[4] = {v0, v1, v2, v3};
#pragma unroll
            for (int i = 0; i < 4; i++) {
                int sl = scA * 4 + i;
                *(short8*)&frag[fb + (sl >> 1) * TS_ + ((sl & 1) << 8) + pbase_rbfA] = rbf8(vv[i]);
            }
            float uu[2] = {u0, u1};
#pragma unroll
            for (int i = 0; i < 2; i++) {
                int sl = scB * 2 + i;
                *(short8*)&frag[fb + (sl >> 1) * TS_ + ((sl & 1) << 8) + pbase_rbfB] = rbf8(uu[i]);
            }
            uint2 sv;
            sv.x = silu2(v0, v1);
            sv.y = silu2(v2, v3);
            *(uint2*)&frag[fb + pbase_siluA] = sv;
            *(unsigned int*)&frag[fb + pbase_siluB] = silu2(u0, u1);
        };

        unsigned short vA[4], uA[2], vB[4], uB[2];
        loadc(0, vA, uA); loadc(1, vB, uB);
        produce(0, vA, uA); produce(1, vB, uB);
        loadc(2, vA, uA); loadc(3, vB, uB);
        block_sync_lds();
        for (int t = 0; t < 12; t++) {
            int cP = 2 * t + 2;
            if (cP     < NC2) produce(cP,     vA, uA);
            if (cP + 1 < NC2) produce(cP + 1, vB, uB);
            int n0 = (cP + 2 < NC2) ? cP + 2 : NC2 - 1;
            int n1 = (cP + 3 < NC2) ? cP + 3 : NC2 - 1;
            loadc(n0, vA, uA); loadc(n1, vB, uB);
            block_sync_lds();
        }
        return;
    }

    // ---------------- consumers ----------------
    __builtin_amdgcn_s_setprio(1);
    int lane = tid & 63;
    int l31 = lane & 31, half = lane >> 5;
    int nt0 = wave * 2;
    int ntn = (wave < 3) ? 2 : 1;
    int off1 = (ntn > 1) ? 64 : 0;           // wave 3 dups its tile slot

    f32x16 acc[3][2];   // [rt][nt]
#pragma unroll
    for (int rt = 0; rt < 3; rt++)
#pragma unroll
        for (int nt = 0; nt < 2; nt++)
#pragma unroll
            for (int i = 0; i < 16; i++) acc[rt][nt][i] = 0.f;

    const short8* wp = (const short8*)w2p;
    short8 wbuf[2][2];

    auto wt0_of = [&](int cc) { return wp + ((size_t)(cc * 9) * NT2 + nt0) * 64 + lane; };
    auto wload = [&](int d, const short8* wt0, int kk) {
        const short8* wt = wt0 + (size_t)kk * (NT2 * 64);
        wbuf[d][0] = wt[0]; wbuf[d][1] = wt[off1];
    };
    auto do_mfma = [&](short8 w0, short8 w1, short8 a0, short8 a1, short8 a2) {
        acc[0][0] = MFMA(w0, a0, acc[0][0]); acc[1][0] = MFMA(w0, a1, acc[1][0]); acc[2][0] = MFMA(w0, a2, acc[2][0]);
        if (ntn == 2) {
            acc[0][1] = MFMA(w1, a0, acc[0][1]); acc[1][1] = MFMA(w1, a1, acc[1][1]); acc[2][1] = MFMA(w1, a2, acc[2][1]);
        }
    };
    auto consume = [&](int cc, const short8* wt0) {   // wbuf[0],[1] preloaded
        const unsigned short* fg = &frag[(cc & 3) * FB_];
        short8 a0 = *(const short8*)&fg[lane * 8];
        short8 a1 = *(const short8*)&fg[512 + lane * 8];
        short8 a2 = *(const short8*)&fg[1024 + lane * 8];
#pragma unroll
        for (int kk = 0; kk < 9; kk++) {
            short8 na0, na1, na2;
            if (kk < 8) {
                na0 = *(const short8*)&fg[(kk + 1) * TS_ + lane * 8];
                na1 = *(const short8*)&fg[(kk + 1) * TS_ + 512 + lane * 8];
                na2 = *(const short8*)&fg[(kk + 1) * TS_ + 1024 + lane * 8];
            }
            short8 w0 = wbuf[kk & 1][0], w1 = wbuf[kk & 1][1];
            if (kk < 7) wload(kk & 1, wt0, kk + 2);
            do_mfma(w0, w1, a0, a1, a2);
            if (kk < 8) { a0 = na0; a1 = na1; a2 = na2; }
        }
    };

    const short8* wtP = wt0_of(0);
    wload(0, wtP, 0); wload(1, wtP, 1);
    block_sync_lds();
    for (int t = 0; t < 12; t++) {
        consume(2 * t, wtP);
        const short8* wtQ = wt0_of(2 * t + 1);
        wload(0, wtQ, 0); wload(1, wtQ, 1);
        consume(2 * t + 1, wtQ);
        int nc = (2 * t + 2 < NC2) ? 2 * t + 2 : NC2 - 1;
        wtP = wt0_of(nc);
        wload(0, wtP, 0); wload(1, wtP, 1);         // prefetch across barrier
        block_sync_lds();
    }

    // epilogue: out[b,p,c] = acc + b2[p] + x[b,p,c]
    int b = blk >> 3;
    int c0 = (blk & 7) * RT_;
#pragma unroll
    for (int nt = 0; nt < 2; nt++) {
        if (nt < ntn) {
            int p0 = (nt0 + nt) * 32 + 4 * half;
#pragma unroll
            for (int reg = 0; reg < 16; reg++) {
                int p = p0 + (reg & 3) + 8 * (reg >> 2);
                if (p < P_) {
                    float bv = b2[p];
#pragma unroll
                    for (int rt = 0; rt < 3; rt++) {
                        size_t off = ((size_t)b * P_ + p) * C_ + c0 + rt * 32 + l31;
                        out[off] = acc[rt][nt][reg] + bv + x[off];
                    }
                }
            }
        }
    }
}

extern "C" void kernel_launch(void* const* d_in, const int* in_sizes, int n_in,
                              void* d_out, int out_size, void* d_ws, size_t ws_size,
                              hipStream_t stream) {
    const float* x   = (const float*)d_in[0];
    const float* w1s = (const float*)d_in[1];
    const float* w1b = (const float*)d_in[2];
    const float* b1  = (const float*)d_in[3];
    const float* w2s = (const float*)d_in[4];
    const float* w2b = (const float*)d_in[5];
    const float* b2  = (const float*)d_in[6];
    float* out = (float*)d_out;

    unsigned short* h1t = (unsigned short*)d_ws;            // 37.75 MB bf16 [n][r]
    unsigned short* w1p = h1t + H1_ELEMS;
    unsigned short* w2p = w1p + W1P_ELEMS;                  // total ~40.7 MB

    int pack_blocks = (int)((W1P_ELEMS + W2P_ELEMS) / 256);
    pack_w_kernel<<<pack_blocks, 256, 0, stream>>>(w1s, w1b, w2s, w2b, w1p, w2p);
    fc1_kernel<<<NB_, 512, 0, stream>>>(x, w1p, b1, h1t);
    fc2_kernel<<<NB_, 512, 0, stream>>>(h1t, w2p, b2, x, out);
}

// Round 7
// 245.286 us; speedup vs baseline: 1.3778x; 1.1873x over previous
//
#include <hip/hip_runtime.h>
#include <cstdint>

#define B_  64
#define P_  196
#define C_  768
#define HS_ 384
#define M_  49152
#define RT_ 96            // r-columns per block (3 rt of 32)
#define NB_ (M_ / RT_)    // 512 blocks = exactly 2/CU

// K-chunk = 16 scalars -> 8 rbf tiles (k16) + 1 silu tile per chunk.
#define NC1 13
#define KT1 111
#define NT1 12
#define NC2 24
#define KT2 216
#define NT2 7

#define H1_ELEMS  ((size_t)M_ * HS_)
#define W1P_ELEMS ((size_t)KT1 * NT1 * 512) // 681,984
#define W2P_ELEMS ((size_t)KT2 * NT2 * 512) // 774,144

typedef __attribute__((ext_vector_type(8)))  short short8;
typedef __attribute__((ext_vector_type(16))) float f32x16;

#define MFMA(w, a, c) __builtin_amdgcn_mfma_f32_32x32x16_bf16((w), (a), (c), 0, 0, 0)

static __device__ __forceinline__ float bf2f(unsigned short u) {
    union { unsigned int i; float f; } v; v.i = ((unsigned int)u) << 16; return v.f;
}
static __device__ __forceinline__ unsigned short f2bf_rne(float f) {
    union { float f; unsigned int i; } v; v.f = f;
    unsigned int r = v.i + 0x7FFFu + ((v.i >> 16) & 1u);
    return (unsigned short)(r >> 16);
}
static __device__ __forceinline__ unsigned int pack2(float a, float b) {
    unsigned int ua = __float_as_uint(a) + 0x8000u;
    unsigned int ub = __float_as_uint(b) + 0x8000u;
    return __builtin_amdgcn_perm(ub, ua, 0x07060302u);  // [a | b] (a = low ushort)
}
// 8 RBF basis: exp(-(3.5s+3.5-j)^2) = exp2(-(u_j)^2), u_j = A*s+A - j*R,
// R = sqrt(log2 e).
static __device__ __forceinline__ short8 rbf8(float s) {
    const float Rr = 1.2011224087864498f;     // sqrt(log2 e)
    const float Aa = 4.2039284307525743f;     // 3.5 * Rr
    float t1 = __builtin_fmaf(Aa, s, Aa);
    union { short8 s8; unsigned int u[4]; } r;
#pragma unroll
    for (int q = 0; q < 4; q++) {
        float u0 = t1 - (float)(2 * q) * Rr;
        float u1 = t1 - (float)(2 * q + 1) * Rr;
        r.u[q] = pack2(__builtin_amdgcn_exp2f(-u0 * u0),
                       __builtin_amdgcn_exp2f(-u1 * u1));
    }
    return r.s8;
}
static __device__ __forceinline__ unsigned int silu2(float a, float b) {
    const float L2E = 1.4426950408889634f;
    float fa = a * __builtin_amdgcn_rcpf(1.f + __builtin_amdgcn_exp2f(-L2E * a));
    float fb = b * __builtin_amdgcn_rcpf(1.f + __builtin_amdgcn_exp2f(-L2E * b));
    return pack2(fa, fb);
}

// lgkm-only barrier: LDS writes must be cross-wave visible, but vmem loads
// to private registers stay in flight across it (no vmcnt(0) drain).
static __device__ __forceinline__ void block_sync_lds() {
    __builtin_amdgcn_sched_barrier(0);
    asm volatile("s_waitcnt lgkmcnt(0)" ::: "memory");
    __builtin_amdgcn_s_barrier();
    __builtin_amdgcn_sched_barrier(0);
}

// Weights packed as A-operand frags in consumption order (unchanged):
// w[tt][nt][lane][j] = W[n = nt*32+(lane&31)][k_logical(tt, khalf=lane>>5, j)]
__global__ void pack_w_kernel(const float* __restrict__ w1s,
                              const float* __restrict__ w1b,
                              const float* __restrict__ w2s,
                              const float* __restrict__ w2b,
                              unsigned short* __restrict__ w1p,
                              unsigned short* __restrict__ w2p) {
    size_t idx = (size_t)blockIdx.x * 256 + threadIdx.x;
    if (idx < W1P_ELEMS) {
        int j    = idx & 7;
        int lane = (idx >> 3) & 63;
        int lin  = idx >> 9;             // tt*NT1 + nt
        int nt   = lin % NT1;
        int tt   = lin / NT1;
        int cc   = (tt < 108) ? tt / 9 : 12;
        int kk   = (tt < 108) ? tt % 9 : (tt - 108);
        int ktl  = (cc < 12) ? kk : ((kk < 2) ? kk : 8);
        int n = nt * 32 + (lane & 31);
        int khalf = lane >> 5;
        float v = 0.f;
        if (ktl < 8) {
            int p = cc * 16 + ktl * 2 + khalf;
            if (p < P_) v = w1s[(size_t)n * 1568 + p * 8 + j];
        } else {
            int p = cc * 16 + khalf * 8 + j;
            if (p < P_) v = w1b[(size_t)n * 196 + p];
        }
        w1p[idx] = f2bf_rne(v);
    } else {
        size_t idx2 = idx - W1P_ELEMS;
        if (idx2 < W2P_ELEMS) {
            int j    = idx2 & 7;
            int lane = (idx2 >> 3) & 63;
            int lin  = idx2 >> 9;        // tt*NT2 + nt
            int nt   = lin % NT2;
            int tt   = lin / NT2;
            int cc   = tt / 9;
            int ktl  = tt % 9;
            int n = nt * 32 + (lane & 31);
            int khalf = lane >> 5;
            float v = 0.f;
            if (n < P_) {
                if (ktl < 8) {
                    int s = cc * 16 + ktl * 2 + khalf;
                    v = w2s[(size_t)n * 3072 + s * 8 + j];
                } else {
                    int s = cc * 16 + khalf * 8 + j;
                    v = w2b[(size_t)n * 384 + s];
                }
            }
            w2p[idx2] = f2bf_rne(v);
        }
    }
}

// frag LDS tile: [rt 3][khalf 2][col 32][8] = 1536 ushort; 9 tiles/buf.
#define TS_  1536
#define FB_  (9 * TS_)   // 13824 ushort per buffer

// fc1: R4 structure unchanged (best known for fc1).
__global__ __launch_bounds__(256, 2)
void fc1_kernel(const float* __restrict__ x,
                const unsigned short* __restrict__ w1p,
                const float* __restrict__ b1,
                unsigned short* __restrict__ h1t) {
    __shared__ __align__(16) unsigned short frag[2 * FB_];
    int blk = blockIdx.x;
    int tid = threadIdx.x;
    int b   = blk >> 3;
    int c0  = (blk & 7) * RT_;
    const float* xb = x + (size_t)b * (P_ * C_);

    int colA = tid & 63, scA = tid >> 6;
    int colB = 64 + (tid & 31), scB = tid >> 5;
    int pbase_rbfA  = ((colA >> 5) << 9) + (colA & 31) * 8;
    int pbase_rbfB  = 1024 + (colB & 31) * 8;
    int pbase_siluA = 8 * TS_ + ((colA >> 5) << 9) + ((scA >> 1) << 8) + (colA & 31) * 8 + (scA & 1) * 4;
    int pbase_siluB = 8 * TS_ + 1024 + ((scB >> 2) << 8) + (colB & 31) * 8 + (scB & 3) * 2;

    int wave = tid >> 6, lane = tid & 63;
    int l31 = lane & 31, half = lane >> 5;
    int nt0 = wave * 3;

    f32x16 acc[3][3];   // [rt][nt]
#pragma unroll
    for (int rt = 0; rt < 3; rt++)
#pragma unroll
        for (int nt = 0; nt < 3; nt++)
#pragma unroll
            for (int i = 0; i < 16; i++) acc[rt][nt][i] = 0.f;

    const short8* wp = (const short8*)w1p;
    short8 wbuf[2][3];

    auto wload = [&](int d, const short8* wt0, int kk) {
        const short8* wt = wt0 + (size_t)kk * (NT1 * 64);
        wbuf[d][0] = wt[0]; wbuf[d][1] = wt[64]; wbuf[d][2] = wt[128];
    };
    auto do_mfma = [&](short8 w0, short8 w1, short8 w2,
                       short8 a0, short8 a1, short8 a2) {
        acc[0][0] = MFMA(w0, a0, acc[0][0]); acc[1][0] = MFMA(w0, a1, acc[1][0]); acc[2][0] = MFMA(w0, a2, acc[2][0]);
        acc[0][1] = MFMA(w1, a0, acc[0][1]); acc[1][1] = MFMA(w1, a1, acc[1][1]); acc[2][1] = MFMA(w1, a2, acc[2][1]);
        acc[0][2] = MFMA(w2, a0, acc[0][2]); acc[1][2] = MFMA(w2, a1, acc[1][2]); acc[2][2] = MFMA(w2, a2, acc[2][2]);
    };
    auto produce = [&](int fb, const float (&ra)[4], const float (&rb2)[2]) {
#pragma unroll
        for (int i = 0; i < 4; i++) {
            int sl = scA * 4 + i;
            *(short8*)&frag[fb + (sl >> 1) * TS_ + ((sl & 1) << 8) + pbase_rbfA] = rbf8(ra[i]);
        }
#pragma unroll
        for (int i = 0; i < 2; i++) {
            int sl = scB * 2 + i;
            *(short8*)&frag[fb + (sl >> 1) * TS_ + ((sl & 1) << 8) + pbase_rbfB] = rbf8(rb2[i]);
        }
        uint2 sv;
        sv.x = silu2(ra[0], ra[1]);
        sv.y = silu2(ra[2], ra[3]);
        *(uint2*)&frag[fb + pbase_siluA] = sv;
        *(unsigned int*)&frag[fb + pbase_siluB] = silu2(rb2[0], rb2[1]);
    };
    auto body = [&](int cc, const float (&rbPA)[4], const float (&rbPB)[2],
                    float (&rbLA)[4], float (&rbLB)[2]) {
        const short8* wt0 = wp + ((size_t)(cc * 9) * NT1 + nt0) * 64 + lane;
        wload(0, wt0, 0); wload(1, wt0, 1);
        int fbP = ((cc + 1) & 1) * FB_;
        const unsigned short* fg = &frag[(cc & 1) * FB_];
        short8 a0 = *(const short8*)&fg[lane * 8];
        short8 a1 = *(const short8*)&fg[512 + lane * 8];
        short8 a2 = *(const short8*)&fg[1024 + lane * 8];
#pragma unroll
        for (int kk = 0; kk < 9; kk++) {
            short8 na0, na1, na2;
            if (kk < 8) {
                na0 = *(const short8*)&fg[(kk + 1) * TS_ + lane * 8];
                na1 = *(const short8*)&fg[(kk + 1) * TS_ + 512 + lane * 8];
                na2 = *(const short8*)&fg[(kk + 1) * TS_ + 1024 + lane * 8];
            }
            short8 w0 = wbuf[kk & 1][0], w1 = wbuf[kk & 1][1], w2 = wbuf[kk & 1][2];
            if (kk < 7) wload(kk & 1, wt0, kk + 2);
            if (kk < 4) {
                int sl = scA * 4 + kk;
                *(short8*)&frag[fbP + (sl >> 1) * TS_ + ((sl & 1) << 8) + pbase_rbfA] = rbf8(rbPA[kk]);
            } else if (kk == 4) {
#pragma unroll
                for (int i = 0; i < 2; i++) {
                    int sl = scB * 2 + i;
                    *(short8*)&frag[fbP + (sl >> 1) * TS_ + ((sl & 1) << 8) + pbase_rbfB] = rbf8(rbPB[i]);
                }
            } else if (kk == 5) {
                uint2 sv;
                sv.x = silu2(rbPA[0], rbPA[1]);
                sv.y = silu2(rbPA[2], rbPA[3]);
                *(uint2*)&frag[fbP + pbase_siluA] = sv;
                *(unsigned int*)&frag[fbP + pbase_siluB] = silu2(rbPB[0], rbPB[1]);
            } else if (kk == 6) {
#pragma unroll
                for (int i = 0; i < 2; i++) {
                    int p = (cc + 2) * 16 + scA * 4 + i;
                    p = (p < P_) ? p : (P_ - 1);
                    rbLA[i] = xb[(size_t)p * C_ + c0 + colA];
                }
            } else if (kk == 7) {
#pragma unroll
                for (int i = 2; i < 4; i++) {
                    int p = (cc + 2) * 16 + scA * 4 + i;
                    p = (p < P_) ? p : (P_ - 1);
                    rbLA[i] = xb[(size_t)p * C_ + c0 + colA];
                }
            } else {
#pragma unroll
                for (int i = 0; i < 2; i++) {
                    int p = (cc + 2) * 16 + scB * 2 + i;
                    p = (p < P_) ? p : (P_ - 1);
                    rbLB[i] = xb[(size_t)p * C_ + c0 + colB];
                }
            }
            do_mfma(w0, w1, w2, a0, a1, a2);
            if (kk < 8) { a0 = na0; a1 = na1; a2 = na2; }
        }
        block_sync_lds();
    };

    float rbA_A[4], rbB_A[4], rbA_B[2], rbB_B[2];
#pragma unroll
    for (int i = 0; i < 4; i++) {
        rbA_A[i] = xb[(size_t)(scA * 4 + i) * C_ + c0 + colA];
        rbB_A[i] = xb[(size_t)(16 + scA * 4 + i) * C_ + c0 + colA];
    }
#pragma unroll
    for (int i = 0; i < 2; i++) {
        rbA_B[i] = xb[(size_t)(scB * 2 + i) * C_ + c0 + colB];
        rbB_B[i] = xb[(size_t)(16 + scB * 2 + i) * C_ + c0 + colB];
    }
    produce(0, rbA_A, rbA_B);   // chunk 0 -> frag[0]
    block_sync_lds();

    for (int c2 = 0; c2 < 6; c2++) {          // chunks 0..11
        body(2 * c2,     rbB_A, rbB_B, rbA_A, rbA_B);
        body(2 * c2 + 1, rbA_A, rbA_B, rbB_A, rbB_B);
    }
    // tail: consume chunk 12 (tiles ktl {0,1,8}; weights linear 108..110)
    {
        const short8* wt0 = wp + ((size_t)108 * NT1 + nt0) * 64 + lane;
        wload(0, wt0, 0); wload(1, wt0, 1);
        const unsigned short* fg = &frag[0];  // chunk 12 parity 0
#pragma unroll
        for (int kk = 0; kk < 3; kk++) {
            short8 w0 = wbuf[kk & 1][0], w1 = wbuf[kk & 1][1], w2 = wbuf[kk & 1][2];
            if (kk == 0) wload(0, wt0, 2);
            int ktl = (kk < 2) ? kk : 8;
            short8 a0 = *(const short8*)&fg[ktl * TS_ + lane * 8];
            short8 a1 = *(const short8*)&fg[ktl * TS_ + 512 + lane * 8];
            short8 a2 = *(const short8*)&fg[ktl * TS_ + 1024 + lane * 8];
            do_mfma(w0, w1, w2, a0, a1, a2);
        }
    }

    // epilogue: h1t[n][r]
#pragma unroll
    for (int nt = 0; nt < 3; nt++) {
        int n0 = (nt0 + nt) * 32 + 4 * half;
#pragma unroll
        for (int reg = 0; reg < 16; reg++) {
            int n = n0 + (reg & 3) + 8 * (reg >> 2);
            float bv = b1[n];
#pragma unroll
            for (int rt = 0; rt < 3; rt++) {
                h1t[(size_t)n * M_ + blk * RT_ + rt * 32 + l31] = f2bf_rne(acc[rt][nt][reg] + bv);
            }
        }
    }
}

// fc2: R7 phase-split. Per chunk: 3 phases of {reg-stage 9 a-frags + 6 w-frags
// + produce slice + rbL loads -> lgkm barrier -> pure-register 18-MFMA cluster
// (setprio 1)}. Clusters touch no memory -> waves/blocks skew into mem/MFMA
// role diversity; 2-buffer LDS stays race-free (af staged to regs pre-barrier).
__global__ __launch_bounds__(256, 2)
void fc2_kernel(const unsigned short* __restrict__ h1t,
                const unsigned short* __restrict__ w2p,
                const float* __restrict__ b2,
                const float* __restrict__ x,
                float* __restrict__ out) {
    __shared__ __align__(16) unsigned short frag[2 * FB_];
    int blk = blockIdx.x;
    int tid = threadIdx.x;
    int rbase = blk * RT_;

    int colA = tid & 63, scA = tid >> 6;
    int colB = 64 + (tid & 31), scB = tid >> 5;
    int pbase_rbfA  = ((colA >> 5) << 9) + (colA & 31) * 8;
    int pbase_rbfB  = 1024 + (colB & 31) * 8;
    int pbase_siluA = 8 * TS_ + ((colA >> 5) << 9) + ((scA >> 1) << 8) + (colA & 31) * 8 + (scA & 1) * 4;
    int pbase_siluB = 8 * TS_ + 1024 + ((scB >> 2) << 8) + (colB & 31) * 8 + (scB & 3) * 2;

    int wave = tid >> 6, lane = tid & 63;
    int l31 = lane & 31, half = lane >> 5;
    int nt0 = wave * 2;
    int ntn = (wave < 3) ? 2 : 1;
    int off1 = (ntn > 1) ? 64 : 0;           // wave 3 dups its tile (discarded)

    f32x16 acc[3][2];   // [rt][nt]
#pragma unroll
    for (int rt = 0; rt < 3; rt++)
#pragma unroll
        for (int nt = 0; nt < 2; nt++)
#pragma unroll
            for (int i = 0; i < 16; i++) acc[rt][nt][i] = 0.f;

    const short8* wp = (const short8*)w2p;
    short8 wbuf[3][2];   // one phase: [kk-in-phase][nt]
    short8 af[3][3];     // one phase: [kk-in-phase][rt]

    auto produce = [&](int fb, const unsigned short (&ra)[4], const unsigned short (&rb2)[2]) {
        float v0 = bf2f(ra[0]), v1 = bf2f(ra[1]), v2 = bf2f(ra[2]), v3 = bf2f(ra[3]);
        float u0 = bf2f(rb2[0]), u1 = bf2f(rb2[1]);
        float vv[4] = {v0, v1, v2, v3};
#pragma unroll
        for (int i = 0; i < 4; i++) {
            int sl = scA * 4 + i;
            *(short8*)&frag[fb + (sl >> 1) * TS_ + ((sl & 1) << 8) + pbase_rbfA] = rbf8(vv[i]);
        }
        float uu[2] = {u0, u1};
#pragma unroll
        for (int i = 0; i < 2; i++) {
            int sl = scB * 2 + i;
            *(short8*)&frag[fb + (sl >> 1) * TS_ + ((sl & 1) << 8) + pbase_rbfB] = rbf8(uu[i]);
        }
        uint2 sv;
        sv.x = silu2(v0, v1);
        sv.y = silu2(v2, v3);
        *(uint2*)&frag[fb + pbase_siluA] = sv;
        *(unsigned int*)&frag[fb + pbase_siluB] = silu2(u0, u1);
    };

    auto body = [&](int cc, const unsigned short (&rbPA)[4], const unsigned short (&rbPB)[2],
                    unsigned short (&rbLA)[4], unsigned short (&rbLB)[2]) {
        bool doProd = (cc + 1 < NC2);
        const unsigned short* fg = &frag[(cc & 1) * FB_];
        int fbP = ((cc + 1) & 1) * FB_;
#pragma unroll
        for (int p = 0; p < 3; p++) {
            // ---- MEM section: stage a-frags + weights to regs; produce slice; rbL ----
#pragma unroll
            for (int k = 0; k < 3; k++) {
                int t = 3 * p + k;
                af[k][0] = *(const short8*)&fg[t * TS_ + lane * 8];
                af[k][1] = *(const short8*)&fg[t * TS_ + 512 + lane * 8];
                af[k][2] = *(const short8*)&fg[t * TS_ + 1024 + lane * 8];
            }
            const short8* wt0 = wp + ((size_t)(cc * 9 + 3 * p) * NT2 + nt0) * 64 + lane;
#pragma unroll
            for (int k = 0; k < 3; k++) {
                const short8* wt = wt0 + (size_t)k * (NT2 * 64);
                wbuf[k][0] = wt[0]; wbuf[k][1] = wt[off1];
            }
            if (p == 0) {
                if (doProd) {
#pragma unroll
                    for (int i = 0; i < 2; i++) {
                        int sl = scA * 4 + i;
                        *(short8*)&frag[fbP + (sl >> 1) * TS_ + ((sl & 1) << 8) + pbase_rbfA] =
                            rbf8(bf2f(rbPA[i]));
                    }
                }
#pragma unroll
                for (int i = 0; i < 2; i++) {
                    int s = (cc + 2) * 16 + scA * 4 + i; s = (s < HS_) ? s : (HS_ - 1);
                    rbLA[i] = h1t[(size_t)s * M_ + rbase + colA];
                }
            } else if (p == 1) {
                if (doProd) {
#pragma unroll
                    for (int i = 2; i < 4; i++) {
                        int sl = scA * 4 + i;
                        *(short8*)&frag[fbP + (sl >> 1) * TS_ + ((sl & 1) << 8) + pbase_rbfA] =
                            rbf8(bf2f(rbPA[i]));
                    }
                }
#pragma unroll
                for (int i = 2; i < 4; i++) {
                    int s = (cc + 2) * 16 + scA * 4 + i; s = (s < HS_) ? s : (HS_ - 1);
                    rbLA[i] = h1t[(size_t)s * M_ + rbase + colA];
                }
            } else {
                if (doProd) {
#pragma unroll
                    for (int i = 0; i < 2; i++) {
                        int sl = scB * 2 + i;
                        *(short8*)&frag[fbP + (sl >> 1) * TS_ + ((sl & 1) << 8) + pbase_rbfB] =
                            rbf8(bf2f(rbPB[i]));
                    }
                    uint2 sv;
                    sv.x = silu2(bf2f(rbPA[0]), bf2f(rbPA[1]));
                    sv.y = silu2(bf2f(rbPA[2]), bf2f(rbPA[3]));
                    *(uint2*)&frag[fbP + pbase_siluA] = sv;
                    *(unsigned int*)&frag[fbP + pbase_siluB] = silu2(bf2f(rbPB[0]), bf2f(rbPB[1]));
                }
#pragma unroll
                for (int i = 0; i < 2; i++) {
                    int s = (cc + 2) * 16 + scB * 2 + i; s = (s < HS_) ? s : (HS_ - 1);
                    rbLB[i] = h1t[(size_t)s * M_ + rbase + colB];
                }
            }
            block_sync_lds();
            // ---- MFMA cluster: pure registers ----
            __builtin_amdgcn_s_setprio(1);
#pragma unroll
            for (int k = 0; k < 3; k++) {
                short8 w0 = wbuf[k][0], w1 = wbuf[k][1];
                acc[0][0] = MFMA(w0, af[k][0], acc[0][0]);
                acc[1][0] = MFMA(w0, af[k][1], acc[1][0]);
                acc[2][0] = MFMA(w0, af[k][2], acc[2][0]);
                if (ntn == 2) {
                    acc[0][1] = MFMA(w1, af[k][0], acc[0][1]);
                    acc[1][1] = MFMA(w1, af[k][1], acc[1][1]);
                    acc[2][1] = MFMA(w1, af[k][2], acc[2][1]);
                }
            }
            __builtin_amdgcn_s_setprio(0);
        }
    };

    unsigned short rbA_A[4], rbB_A[4], rbA_B[2], rbB_B[2];
#pragma unroll
    for (int i = 0; i < 4; i++) {
        rbA_A[i] = h1t[(size_t)(scA * 4 + i) * M_ + rbase + colA];
        rbB_A[i] = h1t[(size_t)(16 + scA * 4 + i) * M_ + rbase + colA];
    }
#pragma unroll
    for (int i = 0; i < 2; i++) {
        rbA_B[i] = h1t[(size_t)(scB * 2 + i) * M_ + rbase + colB];
        rbB_B[i] = h1t[(size_t)(16 + scB * 2 + i) * M_ + rbase + colB];
    }
    produce(0, rbA_A, rbA_B);   // chunk 0 -> frag[0]
    block_sync_lds();

    for (int c2 = 0; c2 < 12; c2++) {        // chunks 0..23
        body(2 * c2,     rbB_A, rbB_B, rbA_A, rbA_B);
        body(2 * c2 + 1, rbA_A, rbA_B, rbB_A, rbB_B);
    }

    // epilogue: out[b,p,c] = acc + b2[p] + x[b,p,c]
    int b = blk >> 3;
    int c0 = (blk & 7) * RT_;
#pragma unroll
    for (int nt = 0; nt < 2; nt++) {
        if (nt < ntn) {
            int p0 = (nt0 + nt) * 32 + 4 * half;
#pragma unroll
            for (int reg = 0; reg < 16; reg++) {
                int p = p0 + (reg & 3) + 8 * (reg >> 2);
                if (p < P_) {
                    float bv = b2[p];
#pragma unroll
                    for (int rt = 0; rt < 3; rt++) {
                        size_t off = ((size_t)b * P_ + p) * C_ + c0 + rt * 32 + l31;
                        out[off] = acc[rt][nt][reg] + bv + x[off];
                    }
                }
            }
        }
    }
}

extern "C" void kernel_launch(void* const* d_in, const int* in_sizes, int n_in,
                              void* d_out, int out_size, void* d_ws, size_t ws_size,
                              hipStream_t stream) {
    const float* x   = (const float*)d_in[0];
    const float* w1s = (const float*)d_in[1];
    const float* w1b = (const float*)d_in[2];
    const float* b1  = (const float*)d_in[3];
    const float* w2s = (const float*)d_in[4];
    const float* w2b = (const float*)d_in[5];
    const float* b2  = (const float*)d_in[6];
    float* out = (float*)d_out;

    unsigned short* h1t = (unsigned short*)d_ws;            // 37.75 MB bf16 [n][r]
    unsigned short* w1p = h1t + H1_ELEMS;
    unsigned short* w2p = w1p + W1P_ELEMS;                  // total ~40.7 MB

    int pack_blocks = (int)((W1P_ELEMS + W2P_ELEMS) / 256);
    pack_w_kernel<<<pack_blocks, 256, 0, stream>>>(w1s, w1b, w2s, w2b, w1p, w2p);
    fc1_kernel<<<NB_, 256, 0, stream>>>(x, w1p, b1, h1t);
    fc2_kernel<<<NB_, 256, 0, stream>>>(h1t, w2p, b2, x, out);
}